// Round 12
// baseline (294.880 us; speedup 1.0000x reference)
//
#include <hip/hip_runtime.h>
#include <stdint.h>

// ---------- types ----------
typedef __attribute__((ext_vector_type(8)))  __bf16 bf16x8;
typedef __attribute__((ext_vector_type(4)))  float  f32x4;
typedef __attribute__((ext_vector_type(16))) float  f32x16;

__device__ __forceinline__ float bf2f(unsigned short u) {
    union { unsigned int i; float f; } v; v.i = ((unsigned int)u) << 16; return v.f;
}
__device__ __forceinline__ unsigned short f2bf(float f) {  // round-to-nearest-even
    unsigned int x = __builtin_bit_cast(unsigned int, f);
    x += 0x7FFFu + ((x >> 16) & 1u);
    return (unsigned short)(x >> 16);
}

// ---------- fp32 -> bf16 cast (vectorized, grid-stride) ----------
__global__ __launch_bounds__(256) void cast_kernel(const float* __restrict__ src,
                                                   unsigned short* __restrict__ dst, int n4) {
    int i = blockIdx.x * blockDim.x + threadIdx.x;
    int stride = gridDim.x * blockDim.x;
    const float4* s4 = (const float4*)src;
    ushort4* d4 = (ushort4*)dst;
    for (; i < n4; i += stride) {
        float4 v = s4[i];
        ushort4 o;
        o.x = f2bf(v.x); o.y = f2bf(v.y); o.z = f2bf(v.z); o.w = f2bf(v.w);
        d4[i] = o;
    }
}

// ---------- fused 3-weight cast (Wth 256x1024, Wph 256x1024, Wg 1024x1024) ----------
__global__ __launch_bounds__(256) void cast3_kernel(const float* __restrict__ a,
                                                    const float* __restrict__ b,
                                                    const float* __restrict__ c,
                                                    unsigned short* __restrict__ dA,
                                                    unsigned short* __restrict__ dB,
                                                    unsigned short* __restrict__ dC) {
    const int i = blockIdx.x * blockDim.x + threadIdx.x;   // 0..393215 (x4 elems)
    const float4* s4; ushort4* d4; int off;
    if (i < 65536)       { s4 = (const float4*)a; d4 = (ushort4*)dA; off = i; }
    else if (i < 131072) { s4 = (const float4*)b; d4 = (ushort4*)dB; off = i - 65536; }
    else                 { s4 = (const float4*)c; d4 = (ushort4*)dC; off = i - 131072; }
    float4 v = s4[off];
    ushort4 o;
    o.x = f2bf(v.x); o.y = f2bf(v.y); o.z = f2bf(v.z); o.w = f2bf(v.w);
    d4[off] = o;
}

// ---------- GEMM (m97 structure, 32x32x16 MFMA): 128x128 tile, 4 waves, 32KB LDS ----------
// C[M,NTOT] = A[M,K] * W[NTOT,K]^T, bf16 in, fp32 accum. 256 threads = 2x2 waves,
// each wave 64x64 output = 2x2 MFMA tiles of 32x32. Single-buffer stage->sync->MFMA->sync;
// latency cover from 4-5 resident blocks/CU (TLP). Chunk-XOR swizzle, XCD map (nt fastest).
// A/B frag: row/col = lane&31, k = (lane>>5)*8 + j (doubled-K pattern).
// C/D frag: col = lane&31, row = (reg&3) + 8*(reg>>2) + 4*(lane>>5)  [HW-verified m74/m101].
// MODE 0: += bias (split col 256), bf16 out via 2-pass LDS-coalesced epilogue.
// MODE 1: relu, fp32 direct stores (128B lines).
template<int NTOT, int MODE, int NTI>
__global__ __launch_bounds__(256, 4)
void gemm97(const unsigned short* __restrict__ A,
            const unsigned short* __restrict__ W,
            const float* __restrict__ bias0,
            const float* __restrict__ bias1,
            unsigned short* __restrict__ outb,
            float* __restrict__ outf) {
    constexpr int K  = 1024;
    constexpr int NT = 16;                         // K-tiles of 64
    __shared__ unsigned short lds[16384];          // A[128][64] | B[128][64] = 32 KB

    const int t    = threadIdx.x;
    const int wave = t >> 6;
    const int lane = t & 63;

    const int bid = blockIdx.x;
    const int xcd = bid & 7;                       // HW round-robins blocks over 8 XCDs
    const int j   = bid >> 3;
    const int mt  = xcd * 48 + j / NTI;            // 384 M-tiles, 48 per XCD
    const int nt  = j % NTI;                       // nt fastest: A-tile reused NTI times

    const int wr = wave >> 1;                      // 0..1 : rows wr*64..
    const int wc = wave & 1;                       // 0..1 : cols wc*64..

    const size_t aBase = (size_t)mt * 128 * K;
    const size_t bBase = (size_t)nt * 128 * K;

    // staging: 256 thr x 16B = 4KB = 32 rows of 128B per instr; pre-swizzled source
    const int srow = t >> 3;                       // 0..31
    const int scol = ((t & 7) ^ (srow & 7)) << 3;  // element offset
    const unsigned short* gA = A + aBase + (size_t)srow * K + scol;
    const unsigned short* gB = W + bBase + (size_t)srow * K + scol;

    auto STAGE = [&](int tile) {                   // 4 instr A + 4 instr B
#pragma unroll
        for (int i = 0; i < 4; ++i)
            __builtin_amdgcn_global_load_lds(
                (const __attribute__((address_space(1))) void*)(gA + (size_t)(i * 32) * K + tile * 64),
                (__attribute__((address_space(3))) void*)(lds + i * 2048 + wave * 512), 16, 0, 0);
#pragma unroll
        for (int i = 0; i < 4; ++i)
            __builtin_amdgcn_global_load_lds(
                (const __attribute__((address_space(1))) void*)(gB + (size_t)(i * 32) * K + tile * 64),
                (__attribute__((address_space(3))) void*)(lds + 8192 + i * 2048 + wave * 512), 16, 0, 0);
    };

    const int lr32 = lane & 31;
    const int hi   = lane >> 5;
    auto LDA = [&](int mi, int kk) -> bf16x8 {     // frag k = kk*16 + hi*8 + [0..8)
        const int row = wr * 64 + mi * 32 + lr32;
        const int ch  = (kk * 2 + hi) ^ (row & 7);
        return *reinterpret_cast<const bf16x8*>(&lds[row * 64 + ch * 8]);
    };
    auto LDB = [&](int ni, int kk) -> bf16x8 {
        const int row = wc * 64 + ni * 32 + lr32;
        const int ch  = (kk * 2 + hi) ^ (row & 7);
        return *reinterpret_cast<const bf16x8*>(&lds[8192 + row * 64 + ch * 8]);
    };

    f32x16 acc[2][2];
#pragma unroll
    for (int m = 0; m < 2; ++m)
#pragma unroll
        for (int n = 0; n < 2; ++n)
#pragma unroll
            for (int r = 0; r < 16; ++r) acc[m][n][r] = 0.f;

    for (int tt = 0; tt < NT; ++tt) {
        STAGE(tt);
        __syncthreads();                           // drains vmcnt(0): tile landed
#pragma unroll
        for (int kk = 0; kk < 4; ++kk) {
            bf16x8 a0 = LDA(0, kk), a1 = LDA(1, kk);
            bf16x8 b0 = LDB(0, kk), b1 = LDB(1, kk);
            acc[0][0] = __builtin_amdgcn_mfma_f32_32x32x16_bf16(a0, b0, acc[0][0], 0, 0, 0);
            acc[0][1] = __builtin_amdgcn_mfma_f32_32x32x16_bf16(a0, b1, acc[0][1], 0, 0, 0);
            acc[1][0] = __builtin_amdgcn_mfma_f32_32x32x16_bf16(a1, b0, acc[1][0], 0, 0, 0);
            acc[1][1] = __builtin_amdgcn_mfma_f32_32x32x16_bf16(a1, b1, acc[1][1], 0, 0, 0);
        }
        __syncthreads();                           // reads done before next stage overwrites
    }

    // -------- epilogue: C/D row = (reg&3) + 8*(reg>>2) + 4*hi, col = lr32 --------
    if (MODE == 1) {
#pragma unroll
        for (int mi = 0; mi < 2; ++mi)
#pragma unroll
            for (int ni = 0; ni < 2; ++ni) {
                const size_t gcol = nt * 128 + wc * 64 + ni * 32 + lr32;
#pragma unroll
                for (int reg = 0; reg < 16; ++reg) {
                    const int rl = (reg & 3) + 8 * (reg >> 2) + 4 * hi;
                    outf[(size_t)(mt * 128 + wr * 64 + mi * 32 + rl) * NTOT + gcol] =
                        fmaxf(acc[mi][ni][reg], 0.f);
                }
            }
    } else {
        // 2-pass (per mi): per wave 32 rows x 72 shorts = 2304; 4 waves = 9216 <= 16384
        unsigned short* lu = lds;
#pragma unroll
        for (int mi = 0; mi < 2; ++mi) {
            __syncthreads();                       // prior reads of lu done
#pragma unroll
            for (int ni = 0; ni < 2; ++ni) {
                const int gc = nt * 128 + wc * 64 + ni * 32 + lr32;
                const float bv = (gc < 256) ? bias0[gc] : bias1[gc - 256];
#pragma unroll
                for (int reg = 0; reg < 16; ++reg) {
                    const int rl = (reg & 3) + 8 * (reg >> 2) + 4 * hi;   // 0..31
                    lu[wave * 2304 + rl * 72 + ni * 32 + lr32] = f2bf(acc[mi][ni][reg] + bv);
                }
            }
            __syncthreads();
            // store 64 global rows (wr in {0,1} x 32 local) x 128 cols bf16 = 8192 shorts
#pragma unroll
            for (int it = 0; it < 4; ++it) {
                const int flat = it * 2048 + t * 8;    // shorts
                const int rp   = flat >> 7;            // 0..63
                const int col  = flat & 127;
                const int wrg  = rp >> 5;              // which wr half
                const int rloc = rp & 31;
                const int reg  = wrg * 2 + (col >> 6); // wave = wr*2 + wc
                uint4 v = *reinterpret_cast<const uint4*>(&lu[reg * 2304 + rloc * 72 + (col & 63)]);
                *reinterpret_cast<uint4*>(outb + (size_t)(mt * 128 + wrg * 64 + mi * 32 + rloc) * NTOT
                                          + nt * 128 + col) = v;
            }
        }
    }
}

// ---------- per-batch: sim -> mask -> softmax -> relation + agg (in-place over x_bf16) ----------
// Vectorized LDS access: float4 dot reads, ushort4 agg reads + packed stores.
__global__ __launch_bounds__(256)
void relation_kernel(const unsigned short* __restrict__ TP,   // [M,512] bf16: theta|phi
                     const float* __restrict__ boxes,         // [M,4]
                     unsigned short* __restrict__ xagg,       // [M,1024] bf16 in, agg out (aliased)
                     float* __restrict__ relout) {            // [BT,12,12] fp32
    __shared__ float th[12][260];   // +4 pad
    __shared__ float ph[12][260];
    __shared__ unsigned short xls[12 * 1024];
    __shared__ float cx[12], cy[12];
    __shared__ float sim[12][12];
    __shared__ float rel[12][12];

    const int b = blockIdx.x;
    const int t = threadIdx.x;

    if (t < 12) {
        const float* bx = boxes + ((size_t)b * 12 + t) * 4;
        cx[t] = (bx[0] + bx[2]) * 0.5f;
        cy[t] = (bx[1] + bx[3]) * 0.5f;
    }
    const uint4* tp4 = (const uint4*)(TP + (size_t)b * 6144);
    for (int c = t; c < 768; c += 256) {
        uint4 v = tp4[c];
        const unsigned short* pv = (const unsigned short*)&v;
        const int n = c >> 6;
        const int c0 = (c & 63) << 3;
        if (c0 < 256) {
#pragma unroll
            for (int jj = 0; jj < 8; ++jj) th[n][c0 + jj] = bf2f(pv[jj]);
        } else {
#pragma unroll
            for (int jj = 0; jj < 8; ++jj) ph[n][c0 - 256 + jj] = bf2f(pv[jj]);
        }
    }
    const uint4* x4 = (const uint4*)(xagg + (size_t)b * 12288);
    uint4* xl4 = (uint4*)xls;
    for (int c = t; c < 1536; c += 256) xl4[c] = x4[c];
    __syncthreads();

    if (t < 144) {
        const int n = t / 12, m = t - (t / 12) * 12;
        const float4* tn = (const float4*)&th[n][0];
        const float4* pm = (const float4*)&ph[m][0];
        float a = 0.f;
#pragma unroll 8
        for (int r = 0; r < 64; ++r) {   // same accumulation order as scalar loop
            float4 av = tn[r], bv4 = pm[r];
            a += av.x * bv4.x; a += av.y * bv4.y; a += av.z * bv4.z; a += av.w * bv4.w;
        }
        const float dx = cx[n] - cx[m], dy = cy[n] - cy[m];
        const float d2 = dx * dx + dy * dy;
        const float thr = 31.4f;  // POS_THRESHOLD * OW
        sim[n][m] = (d2 > thr * thr) ? -__builtin_inff() : a * 0.0625f;
    }
    __syncthreads();

    if (t < 12) {
        float mx = -__builtin_inff();
#pragma unroll
        for (int m = 0; m < 12; ++m) mx = fmaxf(mx, sim[t][m]);
        float e[12]; float s = 0.f;
#pragma unroll
        for (int m = 0; m < 12; ++m) { e[m] = expf(sim[t][m] - mx); s += e[m]; }
        const float inv = 1.f / s;
#pragma unroll
        for (int m = 0; m < 12; ++m) {
            const float r = e[m] * inv;
            rel[t][m] = r;
            relout[(size_t)b * 144 + t * 12 + m] = r;
        }
    }
    __syncthreads();

    unsigned short* aggp = xagg + (size_t)b * 12288;
    {
        const int f0 = t * 4;
        float xv[12][4];
#pragma unroll
        for (int m = 0; m < 12; ++m) {
            ushort4 u = *reinterpret_cast<const ushort4*>(&xls[m * 1024 + f0]);
            xv[m][0] = bf2f(u.x); xv[m][1] = bf2f(u.y);
            xv[m][2] = bf2f(u.z); xv[m][3] = bf2f(u.w);
        }
        float rl[12];
#pragma unroll
        for (int n = 0; n < 12; ++n) {
#pragma unroll
            for (int m = 0; m < 12; ++m) rl[m] = rel[n][m];
            ushort4 o;
            float a0 = 0.f, a1 = 0.f, a2 = 0.f, a3 = 0.f;
#pragma unroll
            for (int m = 0; m < 12; ++m) {
                a0 += rl[m] * xv[m][0];
                a1 += rl[m] * xv[m][1];
                a2 += rl[m] * xv[m][2];
                a3 += rl[m] * xv[m][3];
            }
            o.x = f2bf(a0); o.y = f2bf(a1); o.z = f2bf(a2); o.w = f2bf(a3);
            *reinterpret_cast<ushort4*>(&aggp[n * 1024 + f0]) = o;
        }
    }
}

// ---------- launcher ----------
extern "C" void kernel_launch(void* const* d_in, const int* in_sizes, int n_in,
                              void* d_out, int out_size, void* d_ws, size_t ws_size,
                              hipStream_t stream) {
    const float* x     = (const float*)d_in[0];  // [4096,12,1024] fp32
    const float* boxes = (const float*)d_in[1];  // [49152,4]
    const float* Wth   = (const float*)d_in[2];  // [256,1024]
    const float* bth   = (const float*)d_in[3];  // [256]
    const float* Wph   = (const float*)d_in[4];  // [256,1024]
    const float* bph   = (const float*)d_in[5];  // [256]
    const float* Wg    = (const float*)d_in[6];  // [1024,1024]
    float* out = (float*)d_out;                  // 49152*1024 out | 4096*144 relation

    const int M = 49152;
    const size_t XE = (size_t)M * 1024;

    char* ws = (char*)d_ws;
    unsigned short* xb   = (unsigned short*)ws;                 // bf16 x, later agg (in place)
    unsigned short* TP   = (unsigned short*)(ws + 100663296);   // [M,512] bf16 theta|phi
    unsigned short* Wcat = (unsigned short*)(ws + 150994944);   // [512,1024] bf16
    unsigned short* Wgb  = (unsigned short*)(ws + 152043520);   // [1024,1024] bf16

    cast_kernel<<<2048, 256, 0, stream>>>(x, xb, (int)(XE / 4));
    cast3_kernel<<<1536, 256, 0, stream>>>(Wth, Wph, Wg, Wcat, Wcat + 262144, Wgb);

    // gemm0: 384 M-tiles (48/XCD) x NTI=4 -> 1536 blocks
    gemm97<512, 0, 4><<<dim3(1536), 256, 0, stream>>>(xb, Wcat, bth, bph, TP, nullptr);

    relation_kernel<<<4096, 256, 0, stream>>>(TP, boxes, xb, out + XE);

    // gemm1: 384 M-tiles (48/XCD) x NTI=8 -> 3072 blocks
    gemm97<1024, 1, 8><<<dim3(3072), 256, 0, stream>>>(xb, Wgb, nullptr, nullptr, nullptr, out);
}

// Round 13
// 286.515 us; speedup vs baseline: 1.0292x; 1.0292x over previous
//
#include <hip/hip_runtime.h>
#include <stdint.h>

// ---------- types ----------
typedef __attribute__((ext_vector_type(8))) __bf16 bf16x8;
typedef __attribute__((ext_vector_type(4))) float   f32x4;

__device__ __forceinline__ float bf2f(unsigned short u) {
    union { unsigned int i; float f; } v; v.i = ((unsigned int)u) << 16; return v.f;
}
__device__ __forceinline__ unsigned short f2bf(float f) {  // round-to-nearest-even
    unsigned int x = __builtin_bit_cast(unsigned int, f);
    x += 0x7FFFu + ((x >> 16) & 1u);
    return (unsigned short)(x >> 16);
}

// ---------- fp32 -> bf16 cast (vectorized, grid-stride) ----------
__global__ __launch_bounds__(256) void cast_kernel(const float* __restrict__ src,
                                                   unsigned short* __restrict__ dst, int n4) {
    int i = blockIdx.x * blockDim.x + threadIdx.x;
    int stride = gridDim.x * blockDim.x;
    const float4* s4 = (const float4*)src;
    ushort4* d4 = (ushort4*)dst;
    for (; i < n4; i += stride) {
        float4 v = s4[i];
        ushort4 o;
        o.x = f2bf(v.x); o.y = f2bf(v.y); o.z = f2bf(v.z); o.w = f2bf(v.w);
        d4[i] = o;
    }
}

// ---------- fused 3-weight cast (Wth 256x1024, Wph 256x1024, Wg 1024x1024) ----------
__global__ __launch_bounds__(256) void cast3_kernel(const float* __restrict__ a,
                                                    const float* __restrict__ b,
                                                    const float* __restrict__ c,
                                                    unsigned short* __restrict__ dA,
                                                    unsigned short* __restrict__ dB,
                                                    unsigned short* __restrict__ dC) {
    const int i = blockIdx.x * blockDim.x + threadIdx.x;   // 0..393215 (x4 elems)
    const float4* s4; ushort4* d4; int off;
    if (i < 65536)       { s4 = (const float4*)a; d4 = (ushort4*)dA; off = i; }
    else if (i < 131072) { s4 = (const float4*)b; d4 = (ushort4*)dB; off = i - 65536; }
    else                 { s4 = (const float4*)c; d4 = (ushort4*)dC; off = i - 131072; }
    float4 v = s4[off];
    ushort4 o;
    o.x = f2bf(v.x); o.y = f2bf(v.y); o.z = f2bf(v.z); o.w = f2bf(v.w);
    d4[off] = o;
}

// ---------- GEMM (TLP structure, fat wave tiles): 256x128 tile, 4 waves, 48KB LDS ----------
// C[M,NTOT] = A[M,K] * W[NTOT,K]^T, bf16 in, fp32 accum. 256 threads = 2x2 waves,
// each wave a 128x64 output (2.67 MFMA per frag-read vs 2.0 at 64x64 -> -25% LDS
// bytes/FLOP; kernel is LDS-BW-bound at 39% MfmaUtil in the 64x64 variant).
// Single-buffer stage->sync->MFMA->sync; latency cover from 2 resident blocks/CU.
// Chunk-XOR swizzle (0 conflicts), XCD-aware mapping (nt fastest).
// MODE 0: += bias (split col 256), bf16 out via 2-pass LDS-coalesced epilogue.
// MODE 1: relu, fp32 direct stores.
template<int NTOT, int MODE, int NTI>
__global__ __launch_bounds__(256, 2)
void gemm97(const unsigned short* __restrict__ A,
            const unsigned short* __restrict__ W,
            const float* __restrict__ bias0,
            const float* __restrict__ bias1,
            unsigned short* __restrict__ outb,
            float* __restrict__ outf) {
    constexpr int K  = 1024;
    constexpr int NT = 16;                         // K-tiles of 64
    __shared__ unsigned short lds[24576];          // A[256][64] (32KB) | B[128][64] (16KB)

    const int t    = threadIdx.x;
    const int wave = t >> 6;
    const int lane = t & 63;

    const int bid = blockIdx.x;
    const int xcd = bid & 7;                       // HW round-robins blocks over 8 XCDs
    const int j   = bid >> 3;
    const int mt  = xcd * 24 + j / NTI;            // 192 M-tiles (BM=256), 24 per XCD
    const int nt  = j % NTI;                       // nt fastest: A-tile reused NTI times

    const int wr = wave >> 1;                      // 0..1 : rows wr*128..
    const int wc = wave & 1;                       // 0..1 : cols wc*64..

    const size_t aBase = (size_t)mt * 256 * K;
    const size_t bBase = (size_t)nt * 128 * K;

    // staging: 256 thr x 16B = 4KB = 32 rows of 128B per instr; pre-swizzled source
    const int srow = t >> 3;                       // 0..31
    const int scol = ((t & 7) ^ (srow & 7)) << 3;  // element offset
    const unsigned short* gA = A + aBase + (size_t)srow * K + scol;
    const unsigned short* gB = W + bBase + (size_t)srow * K + scol;

    auto STAGE = [&](int tile) {                   // 8 instr A + 4 instr B
#pragma unroll
        for (int i = 0; i < 8; ++i)
            __builtin_amdgcn_global_load_lds(
                (const __attribute__((address_space(1))) void*)(gA + (size_t)(i * 32) * K + tile * 64),
                (__attribute__((address_space(3))) void*)(lds + i * 2048 + wave * 512), 16, 0, 0);
#pragma unroll
        for (int i = 0; i < 4; ++i)
            __builtin_amdgcn_global_load_lds(
                (const __attribute__((address_space(1))) void*)(gB + (size_t)(i * 32) * K + tile * 64),
                (__attribute__((address_space(3))) void*)(lds + 16384 + i * 2048 + wave * 512), 16, 0, 0);
    };

    const int lr  = lane & 15;
    const int lkc = lane >> 4;
    auto LDA = [&](int mi, int kk) -> bf16x8 {
        const int row = wr * 128 + mi * 16 + lr;
        const int ch  = (kk * 4 + lkc) ^ (row & 7);
        return *reinterpret_cast<const bf16x8*>(&lds[row * 64 + ch * 8]);
    };
    auto LDB = [&](int ni, int kk) -> bf16x8 {
        const int row = wc * 64 + ni * 16 + lr;
        const int ch  = (kk * 4 + lkc) ^ (row & 7);
        return *reinterpret_cast<const bf16x8*>(&lds[16384 + row * 64 + ch * 8]);
    };

    f32x4 acc[8][4];
#pragma unroll
    for (int m = 0; m < 8; ++m)
#pragma unroll
        for (int n = 0; n < 4; ++n) acc[m][n] = f32x4{0.f, 0.f, 0.f, 0.f};

    for (int tt = 0; tt < NT; ++tt) {
        STAGE(tt);
        __syncthreads();                           // drains vmcnt(0): tile landed
        bf16x8 af[8][2], bfr[4][2];
#pragma unroll
        for (int n = 0; n < 4; ++n) { bfr[n][0] = LDB(n, 0); bfr[n][1] = LDB(n, 1); }
#pragma unroll
        for (int m = 0; m < 8; ++m) { af[m][0] = LDA(m, 0); af[m][1] = LDA(m, 1); }
#pragma unroll
        for (int m = 0; m < 8; ++m)
#pragma unroll
            for (int n = 0; n < 4; ++n)
#pragma unroll
                for (int kk = 0; kk < 2; ++kk)
                    acc[m][n] = __builtin_amdgcn_mfma_f32_16x16x32_bf16(af[m][kk], bfr[n][kk], acc[m][n], 0, 0, 0);
        __syncthreads();                           // reads done before next stage overwrites
    }

    // -------- epilogue --------
    const int rowOff = (lane >> 4) * 4;            // C/D: col = lane&15, row = rowOff + r
    if (MODE == 1) {
#pragma unroll
        for (int m = 0; m < 8; ++m)
#pragma unroll
            for (int n = 0; n < 4; ++n)
#pragma unroll
                for (int r = 0; r < 4; ++r)
                    outf[(size_t)(mt * 256 + wr * 128 + m * 16 + rowOff + r) * NTOT
                         + nt * 128 + wc * 64 + n * 16 + lr] = fmaxf(acc[m][n][r], 0.f);
    } else {
        // 2 passes over mi-halves: per pass, wave region 64 rows x 72 shorts = 4608
        unsigned short* lu = lds;
#pragma unroll
        for (int mh = 0; mh < 2; ++mh) {
            __syncthreads();                       // prior reads of lu done
#pragma unroll
            for (int mq = 0; mq < 4; ++mq)
#pragma unroll
                for (int n = 0; n < 4; ++n) {
                    const int gc = nt * 128 + wc * 64 + n * 16 + lr;
                    const float bv = (gc < 256) ? bias0[gc] : bias1[gc - 256];
#pragma unroll
                    for (int r = 0; r < 4; ++r)
                        lu[wave * 4608 + (mq * 16 + rowOff + r) * 72 + n * 16 + lr] =
                            f2bf(acc[mh * 4 + mq][n][r] + bv);
                }
            __syncthreads();
            // store pass: 2 stripes (wr) x 64 rows x 128 cols bf16 = 16384 shorts
#pragma unroll
            for (int it = 0; it < 8; ++it) {
                const int flat = it * 2048 + t * 8;    // shorts
                const int rp   = flat >> 7;            // 0..127
                const int col  = flat & 127;
                const int strp = rp >> 6;              // which wr stripe
                const int rloc = rp & 63;
                const int reg  = strp * 2 + (col >> 6);
                uint4 v = *reinterpret_cast<const uint4*>(&lu[reg * 4608 + rloc * 72 + (col & 63)]);
                *reinterpret_cast<uint4*>(outb + (size_t)(mt * 256 + strp * 128 + mh * 64 + rloc) * NTOT
                                          + nt * 128 + col) = v;
            }
        }
    }
}

// ---------- per-batch: sim -> mask -> softmax -> relation + agg (in-place over x_bf16) ----------
// Vectorized LDS access: float4 dot reads, ushort4 agg reads + packed stores.
__global__ __launch_bounds__(256)
void relation_kernel(const unsigned short* __restrict__ TP,   // [M,512] bf16: theta|phi
                     const float* __restrict__ boxes,         // [M,4]
                     unsigned short* __restrict__ xagg,       // [M,1024] bf16 in, agg out (aliased)
                     float* __restrict__ relout) {            // [BT,12,12] fp32
    __shared__ float th[12][260];   // +4 pad
    __shared__ float ph[12][260];
    __shared__ unsigned short xls[12 * 1024];
    __shared__ float cx[12], cy[12];
    __shared__ float sim[12][12];
    __shared__ float rel[12][12];

    const int b = blockIdx.x;
    const int t = threadIdx.x;

    if (t < 12) {
        const float* bx = boxes + ((size_t)b * 12 + t) * 4;
        cx[t] = (bx[0] + bx[2]) * 0.5f;
        cy[t] = (bx[1] + bx[3]) * 0.5f;
    }
    const uint4* tp4 = (const uint4*)(TP + (size_t)b * 6144);
    for (int c = t; c < 768; c += 256) {
        uint4 v = tp4[c];
        const unsigned short* pv = (const unsigned short*)&v;
        const int n = c >> 6;
        const int c0 = (c & 63) << 3;
        if (c0 < 256) {
#pragma unroll
            for (int jj = 0; jj < 8; ++jj) th[n][c0 + jj] = bf2f(pv[jj]);
        } else {
#pragma unroll
            for (int jj = 0; jj < 8; ++jj) ph[n][c0 - 256 + jj] = bf2f(pv[jj]);
        }
    }
    const uint4* x4 = (const uint4*)(xagg + (size_t)b * 12288);
    uint4* xl4 = (uint4*)xls;
    for (int c = t; c < 1536; c += 256) xl4[c] = x4[c];
    __syncthreads();

    if (t < 144) {
        const int n = t / 12, m = t - (t / 12) * 12;
        const float4* tn = (const float4*)&th[n][0];
        const float4* pm = (const float4*)&ph[m][0];
        float a = 0.f;
#pragma unroll 8
        for (int r = 0; r < 64; ++r) {   // same accumulation order as scalar loop
            float4 av = tn[r], bv4 = pm[r];
            a += av.x * bv4.x; a += av.y * bv4.y; a += av.z * bv4.z; a += av.w * bv4.w;
        }
        const float dx = cx[n] - cx[m], dy = cy[n] - cy[m];
        const float d2 = dx * dx + dy * dy;
        const float thr = 31.4f;  // POS_THRESHOLD * OW
        sim[n][m] = (d2 > thr * thr) ? -__builtin_inff() : a * 0.0625f;
    }
    __syncthreads();

    if (t < 12) {
        float mx = -__builtin_inff();
#pragma unroll
        for (int m = 0; m < 12; ++m) mx = fmaxf(mx, sim[t][m]);
        float e[12]; float s = 0.f;
#pragma unroll
        for (int m = 0; m < 12; ++m) { e[m] = expf(sim[t][m] - mx); s += e[m]; }
        const float inv = 1.f / s;
#pragma unroll
        for (int m = 0; m < 12; ++m) {
            const float r = e[m] * inv;
            rel[t][m] = r;
            relout[(size_t)b * 144 + t * 12 + m] = r;
        }
    }
    __syncthreads();

    unsigned short* aggp = xagg + (size_t)b * 12288;
    {
        const int f0 = t * 4;
        float xv[12][4];
#pragma unroll
        for (int m = 0; m < 12; ++m) {
            ushort4 u = *reinterpret_cast<const ushort4*>(&xls[m * 1024 + f0]);
            xv[m][0] = bf2f(u.x); xv[m][1] = bf2f(u.y);
            xv[m][2] = bf2f(u.z); xv[m][3] = bf2f(u.w);
        }
        float rl[12];
#pragma unroll
        for (int n = 0; n < 12; ++n) {
#pragma unroll
            for (int m = 0; m < 12; ++m) rl[m] = rel[n][m];
            ushort4 o;
            float a0 = 0.f, a1 = 0.f, a2 = 0.f, a3 = 0.f;
#pragma unroll
            for (int m = 0; m < 12; ++m) {
                a0 += rl[m] * xv[m][0];
                a1 += rl[m] * xv[m][1];
                a2 += rl[m] * xv[m][2];
                a3 += rl[m] * xv[m][3];
            }
            o.x = f2bf(a0); o.y = f2bf(a1); o.z = f2bf(a2); o.w = f2bf(a3);
            *reinterpret_cast<ushort4*>(&aggp[n * 1024 + f0]) = o;
        }
    }
}

// ---------- launcher ----------
extern "C" void kernel_launch(void* const* d_in, const int* in_sizes, int n_in,
                              void* d_out, int out_size, void* d_ws, size_t ws_size,
                              hipStream_t stream) {
    const float* x     = (const float*)d_in[0];  // [4096,12,1024] fp32
    const float* boxes = (const float*)d_in[1];  // [49152,4]
    const float* Wth   = (const float*)d_in[2];  // [256,1024]
    const float* bth   = (const float*)d_in[3];  // [256]
    const float* Wph   = (const float*)d_in[4];  // [256,1024]
    const float* bph   = (const float*)d_in[5];  // [256]
    const float* Wg    = (const float*)d_in[6];  // [1024,1024]
    float* out = (float*)d_out;                  // 49152*1024 out | 4096*144 relation

    const int M = 49152;
    const size_t XE = (size_t)M * 1024;

    char* ws = (char*)d_ws;
    unsigned short* xb   = (unsigned short*)ws;                 // bf16 x, later agg (in place)
    unsigned short* TP   = (unsigned short*)(ws + 100663296);   // [M,512] bf16 theta|phi
    unsigned short* Wcat = (unsigned short*)(ws + 150994944);   // [512,1024] bf16
    unsigned short* Wgb  = (unsigned short*)(ws + 152043520);   // [1024,1024] bf16

    cast_kernel<<<2048, 256, 0, stream>>>(x, xb, (int)(XE / 4));
    cast3_kernel<<<1536, 256, 0, stream>>>(Wth, Wph, Wg, Wcat, Wcat + 262144, Wgb);

    // gemm0: 192 M-tiles (24/XCD) x NTI=4 -> 768 blocks
    gemm97<512, 0, 4><<<dim3(768), 256, 0, stream>>>(xb, Wcat, bth, bph, TP, nullptr);

    relation_kernel<<<4096, 256, 0, stream>>>(TP, boxes, xb, out + XE);

    // gemm1: 192 M-tiles (24/XCD) x NTI=8 -> 1536 blocks (3 even rounds at 2/CU)
    gemm97<1024, 1, 8><<<dim3(1536), 256, 0, stream>>>(xb, Wgb, nullptr, nullptr, nullptr, out);
}